// Round 6
// baseline (1339318.555 us; speedup 1.0000x reference)
//
#include <hip/hip_runtime.h>

typedef unsigned short u16;
typedef unsigned int u32;
typedef unsigned long long u64;
typedef short bf16x8 __attribute__((ext_vector_type(8)));
typedef float f32x4 __attribute__((ext_vector_type(4)));

#define Bq 1024
#define Tq 256
#define Dq 128
#define Hq 512
#define GH 2048
#define Zq 64
#define NROW 16            // batch slices (rows), 2 per XCD
#define NCOL 32            // h-col blocks per row
#define MBr 64             // batch rows per block

// workspace layout (bytes)
#define XP_OFF   0ull                      // x packed [T][B][D] bf16  : 67108864 B
#define WP_OFF   (XP_OFF + 67108864ull)    // W/U packed frags 32*81920: 2621440 B
#define HB_OFF   (WP_OFF + 2621440ull)     // h double buffer 2*[B][H] : 2097152 B
#define CT_OFF   (HB_OFF + 2097152ull)     // probe tokens + barrier ctrs: 8192 B

#define POLL_CAP 65536                     // watchdog: never hang, fail loud

__device__ __forceinline__ u16 f2bf(float f){
  unsigned int u = __builtin_bit_cast(unsigned int, f);
  u += 0x7fffu + ((u >> 16) & 1u);          // RNE; inputs finite
  return (u16)(u >> 16);
}
__device__ __forceinline__ float bf2f(u16 v){
  unsigned int u = ((unsigned int)v) << 16;
  return __builtin_bit_cast(float, u);
}
__device__ __forceinline__ float sigmf_(float x){
  return 1.0f / (1.0f + __expf(-x));
}
__device__ __forceinline__ float softplusf_(float x){
  float r = __logf(1.0f + __expf(x));
  return (x > 20.0f) ? x : r;               // guard overflow: softplus(x)->x
}

// agent-coherent 16B load (sc1 path, reads coherence point) -- slow mode
__device__ __forceinline__ bf16x8 ld_h16_agent(const u16* p){
  union { u64 q[2]; bf16x8 v; } u;
  const u64* q = (const u64*)p;
  u.q[0] = __hip_atomic_load(q,     __ATOMIC_RELAXED, __HIP_MEMORY_SCOPE_AGENT);
  u.q[1] = __hip_atomic_load(q + 1, __ATOMIC_RELAXED, __HIP_MEMORY_SCOPE_AGENT);
  return u.v;
}
__device__ __forceinline__ void inv_l1(){
  asm volatile("buffer_inv sc0" ::: "memory");   // L1-only invalidate
}
// sc0 poll load: bypasses L1 only; reads this XCD's L2 (fast-mode barrier)
__device__ __forceinline__ u32 ld_ctr_l2(const u32* p){
  u32 v;
  asm volatile("global_load_dword %0, %1, off sc0\n\ts_waitcnt vmcnt(0)"
               : "=v"(v) : "v"(p) : "memory");
  return v;
}
// agent barrier: arrive + poll, watchdog-capped (slow mode / probe)
__device__ __forceinline__ void agent_bar(u32* c, u32 target){
  u32 old = __hip_atomic_fetch_add(c, 1u, __ATOMIC_RELAXED, __HIP_MEMORY_SCOPE_AGENT);
  if (old + 1u >= target) return;            // last arriver: no poll
  for (int w = 0; w < POLL_CAP; ++w){
    if (__hip_atomic_load(c, __ATOMIC_RELAXED, __HIP_MEMORY_SCOPE_AGENT) >= target) break;
    __builtin_amdgcn_s_sleep(1);
  }
}
// L2-local barrier: workgroup-scope add executes in the shared XCD L2;
// only valid when the placement probe passed (co-XCD verified).
__device__ __forceinline__ void l2_bar(u32* c, u32 target){
  u32 old = __hip_atomic_fetch_add(c, 1u, __ATOMIC_RELAXED, __HIP_MEMORY_SCOPE_WORKGROUP);
  if (old + 1u >= target) return;            // last arriver: no poll
  for (int w = 0; w < POLL_CAP; ++w){
    if (ld_ctr_l2(c) >= target) break;
    __builtin_amdgcn_s_sleep(1);
  }
}

// ---- pack x [B,T,D] fp32 -> [T,B,D] bf16 -------------------------------
__global__ __launch_bounds__(256) void pack_x_k(const float4* __restrict__ x,
                                                ushort4* __restrict__ xp){
  int idx = blockIdx.x * 256 + threadIdx.x;          // 8,388,608 float4s
  int t = idx >> 15, rem = idx & 32767, b = rem >> 5, d4 = rem & 31;
  float4 v = x[(size_t)b * 8192 + t * 32 + d4];
  ushort4 o;
  o.x = f2bf(v.x); o.y = f2bf(v.y); o.z = f2bf(v.z); o.w = f2bf(v.w);
  xp[idx] = o;
}

// ---- pack [W;U] into per-j-block MFMA B-fragment images ----------------
__global__ __launch_bounds__(256) void pack_w_k(const float* __restrict__ W,
                                                const float* __restrict__ U,
                                                u16* __restrict__ wp){
  int idx = blockIdx.x * 256 + threadIdx.x;          // 163840 threads
  int j = idx / 5120; int rem = idx % 5120;
  int kcg = rem >> 8; int rem2 = rem & 255;
  int n = rem2 >> 6; int lane = rem2 & 63;
  int col  = n * Hq + j * 16 + (lane & 15);
  int krow = kcg * 32 + ((lane >> 4) * 8);
  u16 vals[8];
  #pragma unroll
  for (int jj = 0; jj < 8; ++jj){
    int k = krow + jj;
    float v = (k < Dq) ? W[(size_t)k * GH + col] : U[(size_t)(k - Dq) * GH + col];
    vals[jj] = f2bf(v);
  }
  ushort4* dst = (ushort4*)(wp + (size_t)j * 40960 + ((size_t)(kcg * 4 + n) * 64 + lane) * 8);
  dst[0] = make_ushort4(vals[0], vals[1], vals[2], vals[3]);
  dst[1] = make_ushort4(vals[4], vals[5], vals[6], vals[7]);
}

// ---- persistent LSTM recurrence ---------------------------------------
// grid 512: bx -> row i = bx&15 (XCD i&7 via %8 round-robin), col j = bx>>4.
// 2 blocks/CU; each XCD hosts 2 INDEPENDENT rows -> their barrier stalls
// and compute interleave on the same SIMDs. Row's 32 blocks exchange h
// via the shared XCD L2 (fast) or L3 agent path (slow fallback). The
// fast/slow verdict is grid-uniform; every spin is watchdog-capped.
__global__ __launch_bounds__(256, 2) void lstm_k(
    const u16* __restrict__ xp, const u16* __restrict__ wp,
    const float* __restrict__ bias, u16* __restrict__ hb,
    u32* __restrict__ ctr)
{
  __shared__ u16 WL[32768];                 // U-part B-frags, 64 KB
  __shared__ int sbad, sres;
  const int bx = blockIdx.x;
  const int i = bx & 15, j = bx >> 4;       // row (XCD = i&7), col
  const int tid = threadIdx.x;
  const int lane = tid & 63, wv = tid >> 6;
  const int l15 = lane & 15, quad = lane >> 4;
  const int koff = quad * 8;

  u32* tok   = ctr;                         // [512] placement tokens
  u32* pc1   = ctr + 528;                   // probe barrier 1
  u32* pc2   = ctr + 544;                   // probe barrier 2
  u32* bad   = ctr + 560;                   // global verdict (0 = all ok)
  u32* stepc = ctr + 1024 + i * 64;         // per-row step ctr, 256 B apart

  // ---- placement probe ----
  u32 xcc = __builtin_amdgcn_s_getreg(63508) & 0xffu; // hwreg(HW_REG_XCC_ID=20,0,32)
  if (tid == 0){
    tok[bx] = (xcc << 16) | ((u32)(bx + 1) & 0xffffu);  // plain store -> local L2
    sbad = 0;
  }
  __syncthreads();                           // drains vmcnt; compiler barrier
  if (tid == 0) agent_bar(pc1, NROW * NCOL);
  __syncthreads();
  inv_l1();
  if (tid < NCOL){
    // row i, col tid was written by block bx' = tid*16 + i; plain load only
    // sees correct token if that block shares our L2 (xcc tag must match).
    u32 v = tok[tid * 16 + i];
    u32 expect = (xcc << 16) | ((u32)(tid * 16 + i + 1) & 0xffffu);
    if (v != expect) atomicOr(&sbad, 1);
  }
  __syncthreads();
  if (tid == 0){
    if (sbad) __hip_atomic_fetch_or(bad, 1u, __ATOMIC_RELAXED, __HIP_MEMORY_SCOPE_AGENT);
    agent_bar(pc2, NROW * NCOL);             // all verdicts merged
    sres = (int)__hip_atomic_load(bad, __ATOMIC_RELAXED, __HIP_MEMORY_SCOPE_AGENT);
  }
  __syncthreads();
  const bool fast = (sres == 0);             // grid-uniform decision

  // x-part weights (K=0..127) -> registers: wx[kc][n]
  const u16* wj = wp + (size_t)j * 40960;
  bf16x8 wx[4][4];
  #pragma unroll
  for (int kc = 0; kc < 4; ++kc)
    #pragma unroll
    for (int n = 0; n < 4; ++n)
      wx[kc][n] = *(const bf16x8*)(wj + ((kc * 4 + n) * 64 + lane) * 8);

  // U-part weights (K=128..639) -> LDS
  {
    const uint4* src = (const uint4*)(wj + 8192);
    uint4* dst = (uint4*)WL;
    #pragma unroll
    for (int q = 0; q < 16; ++q) dst[tid + q * 256] = src[tid + q * 256];
  }
  __syncthreads();

  const int hc = j * 16 + l15;
  const float bi  = bias[hc];
  const float bf_ = bias[Hq + hc];
  const float bg  = bias[2 * Hq + hc];
  const float bo  = bias[3 * Hq + hc];
  const int row0 = i * MBr + wv * 16 + l15; // this wave's A-rows
  float cst[4] = {0.f, 0.f, 0.f, 0.f};

  for (int t = 0; t < Tq; ++t){
    f32x4 acc[4];
    #pragma unroll
    for (int n = 0; n < 4; ++n) acc[n] = (f32x4){0.f, 0.f, 0.f, 0.f};

    // ---- h loads first: latency overlaps x loads + part-1 MFMAs ----
    bf16x8 ah[16];
    if (t > 0){
      const u16* hcur = hb + (size_t)(t & 1) * (Bq * Hq);
      if (fast){
        #pragma unroll
        for (int kc = 0; kc < 16; ++kc)      // plain dwordx4: local-L2 hits
          ah[kc] = *(const bf16x8*)(hcur + (size_t)row0 * Hq + kc * 32 + koff);
      } else {
        #pragma unroll
        for (int kc = 0; kc < 16; ++kc)
          ah[kc] = ld_h16_agent(hcur + (size_t)row0 * Hq + kc * 32 + koff);
      }
    }

    // ---- K part 1: x_t (kc 0..3), B from registers ----
    const u16* xt = xp + (size_t)t * (Bq * Dq);
    bf16x8 ax[4];
    #pragma unroll
    for (int kc = 0; kc < 4; ++kc)
      ax[kc] = *(const bf16x8*)(xt + (size_t)row0 * Dq + kc * 32 + koff);
    #pragma unroll
    for (int kc = 0; kc < 4; ++kc)
      #pragma unroll
      for (int n = 0; n < 4; ++n)
        acc[n] = __builtin_amdgcn_mfma_f32_16x16x32_bf16(ax[kc], wx[kc][n], acc[n], 0, 0, 0);

    // ---- K part 2: h_t (kc 0..15), B from LDS ----
    if (t > 0){
      #pragma unroll
      for (int kc = 0; kc < 16; ++kc){
        #pragma unroll
        for (int n = 0; n < 4; ++n){
          bf16x8 bw = *(const bf16x8*)(WL + ((kc * 4 + n) * 64 + lane) * 8);
          acc[n] = __builtin_amdgcn_mfma_f32_16x16x32_bf16(ah[kc], bw, acc[n], 0, 0, 0);
        }
      }
    }

    // ---- gate epilogue; c in registers; h stores (mode-dependent) ----
    // C-layout: col = lane&15 (= h-col), row = quad*4 + reg  [m89/m91]
    u16* hn = hb + (size_t)((t + 1) & 1) * (Bq * Hq);
    #pragma unroll
    for (int r = 0; r < 4; ++r){
      float gi = acc[0][r] + bi;
      float gf = acc[1][r] + bf_;
      float gg = acc[2][r] + bg;
      float go = acc[3][r] + bo;
      float iv = sigmf_(gi), fv = sigmf_(gf);
      float gv = softplusf_(gg), ov = sigmf_(go);
      float cn = fv * cst[r] + iv * gv;
      cst[r] = cn;
      float hv = ov * softplusf_(cn);
      int row = i * MBr + wv * 16 + quad * 4 + r;
      u16* dst = hn + (size_t)row * Hq + hc;
      if (fast) *dst = f2bf(hv);            // plain store -> local L2
      else __hip_atomic_store(dst, f2bf(hv), __ATOMIC_RELAXED, __HIP_MEMORY_SCOPE_AGENT);
    }

    // ---- row barrier: L2-local in fast mode, agent in slow mode ----
    if (t + 1 < Tq){
      __syncthreads();                       // vmcnt(0): h stores in L2
      u32 target = (u32)(NCOL * (t + 1));
      if (fast){
        if (tid == 0) l2_bar(stepc, target);
        __syncthreads();
        inv_l1();                            // drop stale h lines from L1
      } else {
        if (tid == 0) agent_bar(stepc, target);
        __syncthreads();
      }
    }
  }
}

// ---- final projection: mu, logvar, z ----------------------------------
__global__ __launch_bounds__(64) void proj_k(const u16* __restrict__ h0,
    const float* __restrict__ Wm, const float* __restrict__ bm,
    const float* __restrict__ Wv, const float* __restrict__ bv,
    const float* __restrict__ eps, float* __restrict__ out)
{
  __shared__ float hs[Hq];
  int b = blockIdx.x, lane = threadIdx.x;
  const u16* hr = h0 + (size_t)b * Hq;
  #pragma unroll
  for (int q = 0; q < 8; ++q) hs[lane * 8 + q] = bf2f(hr[lane * 8 + q]);
  __syncthreads();
  float am = 0.f, av = 0.f;
  #pragma unroll 8
  for (int k = 0; k < Hq; ++k){
    float h = hs[k];
    am = fmaf(h, Wm[(size_t)k * Zq + lane], am);
    av = fmaf(h, Wv[(size_t)k * Zq + lane], av);
  }
  float mu = am + bm[lane];
  float lv = av + bv[lane];
  float z  = mu + eps[(size_t)b * Zq + lane] * expf(0.5f * lv);
  size_t o = (size_t)b * Zq + lane;
  out[o]           = mu;
  out[65536 + o]   = lv;
  out[131072 + o]  = z;
}

extern "C" void kernel_launch(void* const* d_in, const int* in_sizes, int n_in,
                              void* d_out, int out_size, void* d_ws, size_t ws_size,
                              hipStream_t stream)
{
  const float* x   = (const float*)d_in[0];
  const float* eps = (const float*)d_in[1];
  const float* W   = (const float*)d_in[2];
  const float* U   = (const float*)d_in[3];
  const float* bb  = (const float*)d_in[4];
  const float* Wm  = (const float*)d_in[5];
  const float* bm  = (const float*)d_in[6];
  const float* Wv  = (const float*)d_in[7];
  const float* bv  = (const float*)d_in[8];

  char* ws = (char*)d_ws;
  u16* xp = (u16*)(ws + XP_OFF);
  u16* wp = (u16*)(ws + WP_OFF);
  u16* hb = (u16*)(ws + HB_OFF);
  u32* ctr = (u32*)(ws + CT_OFF);

  hipMemsetAsync(ctr, 0, 8192, stream);
  pack_x_k<<<32768, 256, 0, stream>>>((const float4*)x, (ushort4*)xp);
  pack_w_k<<<640, 256, 0, stream>>>(W, U, wp);
  lstm_k<<<NROW * NCOL, 256, 0, stream>>>(xp, wp, bb, hb, ctr);
  // after 256 steps, h_last sits in parity (256 & 1) == 0
  proj_k<<<Bq, 64, 0, stream>>>(hb, Wm, bm, Wv, bv, eps, (float*)d_out);
}

// Round 7
// 1940.102 us; speedup vs baseline: 690.3341x; 690.3341x over previous
//
#include <hip/hip_runtime.h>

typedef unsigned short u16;
typedef unsigned int u32;
typedef unsigned long long u64;
typedef short bf16x8 __attribute__((ext_vector_type(8)));
typedef float f32x4 __attribute__((ext_vector_type(4)));

#define Bq 1024
#define Tq 256
#define Dq 128
#define Hq 512
#define GH 2048
#define Zq 64
#define NROW 16            // batch slices (rows), 2 per XCD
#define NCOL 32            // h-col blocks per row
#define MBr 64             // batch rows per block

// workspace layout (bytes)
#define XP_OFF   0ull                      // x packed [T][B][D] bf16  : 67108864 B
#define WP_OFF   (XP_OFF + 67108864ull)    // W/U packed frags 32*81920: 2621440 B
#define HB_OFF   (WP_OFF + 2621440ull)     // h double buffer 2*[B][H] : 2097152 B
#define CT_OFF   (HB_OFF + 2097152ull)     // probe tokens + barrier ctrs: 8192 B

#define POLL_CAP 65536                     // watchdog: never hang, fail loud

__device__ __forceinline__ u16 f2bf(float f){
  unsigned int u = __builtin_bit_cast(unsigned int, f);
  u += 0x7fffu + ((u >> 16) & 1u);          // RNE; inputs finite
  return (u16)(u >> 16);
}
__device__ __forceinline__ float bf2f(u16 v){
  unsigned int u = ((unsigned int)v) << 16;
  return __builtin_bit_cast(float, u);
}
__device__ __forceinline__ float sigmf_(float x){
  return 1.0f / (1.0f + __expf(-x));
}
__device__ __forceinline__ float softplusf_(float x){
  float r = __logf(1.0f + __expf(x));
  return (x > 20.0f) ? x : r;               // guard overflow: softplus(x)->x
}

// agent-coherent 16B load (sc1 path, reads coherence point) -- slow mode
__device__ __forceinline__ bf16x8 ld_h16_agent(const u16* p){
  union { u64 q[2]; bf16x8 v; } u;
  const u64* q = (const u64*)p;
  u.q[0] = __hip_atomic_load(q,     __ATOMIC_RELAXED, __HIP_MEMORY_SCOPE_AGENT);
  u.q[1] = __hip_atomic_load(q + 1, __ATOMIC_RELAXED, __HIP_MEMORY_SCOPE_AGENT);
  return u.v;
}
__device__ __forceinline__ void inv_l1(){
  asm volatile("buffer_inv sc0" ::: "memory");   // L1-only invalidate
}
// agent barrier pieces (PROVEN in R5): arrive at L3, poll via agent atomic
// load (sc1 -> bypasses L1+L2, can never read a stale cached line).
__device__ __forceinline__ u32 bar_arrive(u32* c){
  return __hip_atomic_fetch_add(c, 1u, __ATOMIC_RELAXED, __HIP_MEMORY_SCOPE_AGENT);
}
__device__ __forceinline__ void bar_poll(u32* c, u32 target){
  for (int w = 0; w < POLL_CAP; ++w){
    if (__hip_atomic_load(c, __ATOMIC_RELAXED, __HIP_MEMORY_SCOPE_AGENT) >= target) break;
    __builtin_amdgcn_s_sleep(1);
  }
}
__device__ __forceinline__ void agent_bar(u32* c, u32 target){
  u32 old = bar_arrive(c);
  if (old + 1u >= target) return;            // last arriver: no poll
  bar_poll(c, target);
}

// ---- pack x [B,T,D] fp32 -> [T,B,D] bf16 -------------------------------
__global__ __launch_bounds__(256) void pack_x_k(const float4* __restrict__ x,
                                                ushort4* __restrict__ xp){
  int idx = blockIdx.x * 256 + threadIdx.x;          // 8,388,608 float4s
  int t = idx >> 15, rem = idx & 32767, b = rem >> 5, d4 = rem & 31;
  float4 v = x[(size_t)b * 8192 + t * 32 + d4];
  ushort4 o;
  o.x = f2bf(v.x); o.y = f2bf(v.y); o.z = f2bf(v.z); o.w = f2bf(v.w);
  xp[idx] = o;
}

// ---- pack [W;U] into per-j-block MFMA B-fragment images ----------------
__global__ __launch_bounds__(256) void pack_w_k(const float* __restrict__ W,
                                                const float* __restrict__ U,
                                                u16* __restrict__ wp){
  int idx = blockIdx.x * 256 + threadIdx.x;          // 163840 threads
  int j = idx / 5120; int rem = idx % 5120;
  int kcg = rem >> 8; int rem2 = rem & 255;
  int n = rem2 >> 6; int lane = rem2 & 63;
  int col  = n * Hq + j * 16 + (lane & 15);
  int krow = kcg * 32 + ((lane >> 4) * 8);
  u16 vals[8];
  #pragma unroll
  for (int jj = 0; jj < 8; ++jj){
    int k = krow + jj;
    float v = (k < Dq) ? W[(size_t)k * GH + col] : U[(size_t)(k - Dq) * GH + col];
    vals[jj] = f2bf(v);
  }
  ushort4* dst = (ushort4*)(wp + (size_t)j * 40960 + ((size_t)(kcg * 4 + n) * 64 + lane) * 8);
  dst[0] = make_ushort4(vals[0], vals[1], vals[2], vals[3]);
  dst[1] = make_ushort4(vals[4], vals[5], vals[6], vals[7]);
}

// ---- persistent LSTM recurrence ---------------------------------------
// grid 512: bx -> row i = bx&15 (XCD i&7 via %8 round-robin), col j = bx>>4.
// 2 blocks/CU; each XCD hosts 2 INDEPENDENT rows whose barrier stalls and
// compute interleave on the same SIMDs. h exchange: plain st/ld through
// the shared XCD L2 (fast, probe-verified) or agent path (slow fallback).
// Barrier protocol (R5-proven agent arrive/poll) is IDENTICAL in both
// modes; next step's x-GEMM runs in the barrier shadow. Watchdog-capped.
__global__ __launch_bounds__(256, 2) void lstm_k(
    const u16* __restrict__ xp, const u16* __restrict__ wp,
    const float* __restrict__ bias, u16* __restrict__ hb,
    u32* __restrict__ ctr)
{
  __shared__ u16 WL[32768];                 // U-part B-frags, 64 KB
  __shared__ int sbad, sres;
  const int bx = blockIdx.x;
  const int i = bx & 15, j = bx >> 4;       // row (XCD = i&7), col
  const int tid = threadIdx.x;
  const int lane = tid & 63, wv = tid >> 6;
  const int l15 = lane & 15, quad = lane >> 4;
  const int koff = quad * 8;

  u32* tok   = ctr;                         // [512] placement tokens
  u32* pc1   = ctr + 528;                   // probe barrier 1
  u32* pc2   = ctr + 544;                   // probe barrier 2
  u32* bad   = ctr + 560;                   // global verdict (0 = all ok)
  u32* stepc = ctr + 1024 + i * 64;         // per-row step ctr, 256 B apart

  // ---- placement probe ----
  u32 xcc = __builtin_amdgcn_s_getreg(63508) & 0xffu; // hwreg(HW_REG_XCC_ID=20,0,32)
  if (tid == 0){
    tok[bx] = (xcc << 16) | ((u32)(bx + 1) & 0xffffu);  // plain store -> local L2
    sbad = 0;
  }
  __syncthreads();                           // drains vmcnt; compiler barrier
  if (tid == 0) agent_bar(pc1, NROW * NCOL);
  __syncthreads();
  inv_l1();
  if (tid < NCOL){
    // row i, col tid was written by block bx' = tid*16 + i; plain load sees
    // the correct xcc-tagged token only if that block shares our L2.
    u32 v = tok[tid * 16 + i];
    u32 expect = (xcc << 16) | ((u32)(tid * 16 + i + 1) & 0xffffu);
    if (v != expect) atomicOr(&sbad, 1);
  }
  __syncthreads();
  if (tid == 0){
    if (sbad) __hip_atomic_fetch_or(bad, 1u, __ATOMIC_RELAXED, __HIP_MEMORY_SCOPE_AGENT);
    agent_bar(pc2, NROW * NCOL);             // all verdicts merged
    sres = (int)__hip_atomic_load(bad, __ATOMIC_RELAXED, __HIP_MEMORY_SCOPE_AGENT);
  }
  __syncthreads();
  const bool fast = (sres == 0);             // grid-uniform decision

  // x-part weights (K=0..127) -> registers: wx[kc][n]
  const u16* wj = wp + (size_t)j * 40960;
  bf16x8 wx[4][4];
  #pragma unroll
  for (int kc = 0; kc < 4; ++kc)
    #pragma unroll
    for (int n = 0; n < 4; ++n)
      wx[kc][n] = *(const bf16x8*)(wj + ((kc * 4 + n) * 64 + lane) * 8);

  // U-part weights (K=128..639) -> LDS
  {
    const uint4* src = (const uint4*)(wj + 8192);
    uint4* dst = (uint4*)WL;
    #pragma unroll
    for (int q = 0; q < 16; ++q) dst[tid + q * 256] = src[tid + q * 256];
  }
  __syncthreads();

  const int hc = j * 16 + l15;
  const float bi  = bias[hc];
  const float bf_ = bias[Hq + hc];
  const float bg  = bias[2 * Hq + hc];
  const float bo  = bias[3 * Hq + hc];
  const int row0 = i * MBr + wv * 16 + l15; // this wave's A-rows
  float cst[4] = {0.f, 0.f, 0.f, 0.f};

  // ---- x-part for t=0 (pre-loop) ----
  f32x4 acc[4];
  #pragma unroll
  for (int n = 0; n < 4; ++n) acc[n] = (f32x4){0.f, 0.f, 0.f, 0.f};
  {
    bf16x8 ax[4];
    #pragma unroll
    for (int kc = 0; kc < 4; ++kc)
      ax[kc] = *(const bf16x8*)(xp + (size_t)row0 * Dq + kc * 32 + koff);
    #pragma unroll
    for (int kc = 0; kc < 4; ++kc)
      #pragma unroll
      for (int n = 0; n < 4; ++n)
        acc[n] = __builtin_amdgcn_mfma_f32_16x16x32_bf16(ax[kc], wx[kc][n], acc[n], 0, 0, 0);
  }

  for (int t = 0; t < Tq; ++t){
    // acc already holds the x-part for step t (pre-loop or barrier shadow).

    // ---- K part 2: h_t (kc 0..15), B from LDS ----
    if (t > 0){
      const u16* hcur = hb + (size_t)(t & 1) * (Bq * Hq);
      bf16x8 ah[16];
      if (fast){
        #pragma unroll
        for (int kc = 0; kc < 16; ++kc)      // plain dwordx4: local-L2 hits
          ah[kc] = *(const bf16x8*)(hcur + (size_t)row0 * Hq + kc * 32 + koff);
      } else {
        #pragma unroll
        for (int kc = 0; kc < 16; ++kc)
          ah[kc] = ld_h16_agent(hcur + (size_t)row0 * Hq + kc * 32 + koff);
      }
      #pragma unroll
      for (int kc = 0; kc < 16; ++kc){
        #pragma unroll
        for (int n = 0; n < 4; ++n){
          bf16x8 bw = *(const bf16x8*)(WL + ((kc * 4 + n) * 64 + lane) * 8);
          acc[n] = __builtin_amdgcn_mfma_f32_16x16x32_bf16(ah[kc], bw, acc[n], 0, 0, 0);
        }
      }
    }

    // ---- gate epilogue; c in registers; h stores (mode-dependent) ----
    // C-layout: col = lane&15 (= h-col), row = quad*4 + reg  [m89/m91]
    u16* hn = hb + (size_t)((t + 1) & 1) * (Bq * Hq);
    #pragma unroll
    for (int r = 0; r < 4; ++r){
      float gi = acc[0][r] + bi;
      float gf = acc[1][r] + bf_;
      float gg = acc[2][r] + bg;
      float go = acc[3][r] + bo;
      float iv = sigmf_(gi), fv = sigmf_(gf);
      float gv = softplusf_(gg), ov = sigmf_(go);
      float cn = fv * cst[r] + iv * gv;
      cst[r] = cn;
      float hv = ov * softplusf_(cn);
      int row = i * MBr + wv * 16 + quad * 4 + r;
      u16* dst = hn + (size_t)row * Hq + hc;
      if (fast) *dst = f2bf(hv);            // plain store -> local L2
      else __hip_atomic_store(dst, f2bf(hv), __ATOMIC_RELAXED, __HIP_MEMORY_SCOPE_AGENT);
    }

    // ---- barrier with x-GEMM of t+1 in its shadow ----
    if (t + 1 < Tq){
      __syncthreads();                       // vmcnt(0): h stores in L2/L3
      u32 target = (u32)(NCOL * (t + 1));
      u32 old = 0;
      if (tid == 0) old = bar_arrive(stepc); // announce early

      // shadow work: x fragments + x-part MFMAs for step t+1 (h-independent)
      #pragma unroll
      for (int n = 0; n < 4; ++n) acc[n] = (f32x4){0.f, 0.f, 0.f, 0.f};
      {
        const u16* xt2 = xp + (size_t)(t + 1) * (Bq * Dq);
        bf16x8 ax[4];
        #pragma unroll
        for (int kc = 0; kc < 4; ++kc)
          ax[kc] = *(const bf16x8*)(xt2 + (size_t)row0 * Dq + kc * 32 + koff);
        #pragma unroll
        for (int kc = 0; kc < 4; ++kc)
          #pragma unroll
          for (int n = 0; n < 4; ++n)
            acc[n] = __builtin_amdgcn_mfma_f32_16x16x32_bf16(ax[kc], wx[kc][n], acc[n], 0, 0, 0);
      }

      if (tid == 0 && old + 1u < target) bar_poll(stepc, target);
      __syncthreads();
      if (fast) inv_l1();                    // drop stale h lines from L1
    }
  }
}

// ---- final projection: mu, logvar, z ----------------------------------
__global__ __launch_bounds__(64) void proj_k(const u16* __restrict__ h0,
    const float* __restrict__ Wm, const float* __restrict__ bm,
    const float* __restrict__ Wv, const float* __restrict__ bv,
    const float* __restrict__ eps, float* __restrict__ out)
{
  __shared__ float hs[Hq];
  int b = blockIdx.x, lane = threadIdx.x;
  const u16* hr = h0 + (size_t)b * Hq;
  #pragma unroll
  for (int q = 0; q < 8; ++q) hs[lane * 8 + q] = bf2f(hr[lane * 8 + q]);
  __syncthreads();
  float am = 0.f, av = 0.f;
  #pragma unroll 8
  for (int k = 0; k < Hq; ++k){
    float h = hs[k];
    am = fmaf(h, Wm[(size_t)k * Zq + lane], am);
    av = fmaf(h, Wv[(size_t)k * Zq + lane], av);
  }
  float mu = am + bm[lane];
  float lv = av + bv[lane];
  float z  = mu + eps[(size_t)b * Zq + lane] * expf(0.5f * lv);
  size_t o = (size_t)b * Zq + lane;
  out[o]           = mu;
  out[65536 + o]   = lv;
  out[131072 + o]  = z;
}

extern "C" void kernel_launch(void* const* d_in, const int* in_sizes, int n_in,
                              void* d_out, int out_size, void* d_ws, size_t ws_size,
                              hipStream_t stream)
{
  const float* x   = (const float*)d_in[0];
  const float* eps = (const float*)d_in[1];
  const float* W   = (const float*)d_in[2];
  const float* U   = (const float*)d_in[3];
  const float* bb  = (const float*)d_in[4];
  const float* Wm  = (const float*)d_in[5];
  const float* bm  = (const float*)d_in[6];
  const float* Wv  = (const float*)d_in[7];
  const float* bv  = (const float*)d_in[8];

  char* ws = (char*)d_ws;
  u16* xp = (u16*)(ws + XP_OFF);
  u16* wp = (u16*)(ws + WP_OFF);
  u16* hb = (u16*)(ws + HB_OFF);
  u32* ctr = (u32*)(ws + CT_OFF);

  hipMemsetAsync(ctr, 0, 8192, stream);
  pack_x_k<<<32768, 256, 0, stream>>>((const float4*)x, (ushort4*)xp);
  pack_w_k<<<640, 256, 0, stream>>>(W, U, wp);
  lstm_k<<<NROW * NCOL, 256, 0, stream>>>(xp, wp, bb, hb, ctr);
  // after 256 steps, h_last sits in parity (256 & 1) == 0
  proj_k<<<Bq, 64, 0, stream>>>(hb, Wm, bm, Wv, bv, eps, (float*)d_out);
}